// Round 9
// baseline (547.447 us; speedup 1.0000x reference)
//
#include <hip/hip_runtime.h>
#include <hip/hip_fp16.h>
#include <cstdint>
#include <cstddef>

#define B_ROWS 16384
#define DX 128
#define DYDIM 128
#define HDIM 2048
#define NPARAM 49              // 3K+1
#define NCOL 6272              // DYDIM*NPARAM
#define NTILES 26              // ceil(128 dims / 5 dims-per-tile)
#define W2PROWS (NTILES * 256) // 6656 permuted W2 rows

typedef __attribute__((ext_vector_type(8))) _Float16 half8v;
typedef __attribute__((ext_vector_type(4))) float f32x4;

// ---------------- prep kernels ----------------
__global__ void k_f32_to_f16(const float* __restrict__ in, _Float16* __restrict__ out, int n) {
  int i = blockIdx.x * 256 + threadIdx.x;
  if (i < n) out[i] = (_Float16)in[i];
}

__global__ void k_transpose_f16(const float* __restrict__ in, _Float16* __restrict__ out, int R, int C) {
  __shared__ float tile[32][33];
  int c0 = blockIdx.x * 32, r0 = blockIdx.y * 32;
  int tx = threadIdx.x;
  for (int i = threadIdx.y; i < 32; i += 8)
    tile[i][tx] = in[(size_t)(r0 + i) * C + c0 + tx];
  __syncthreads();
  for (int i = threadIdx.y; i < 32; i += 8)
    out[(size_t)(c0 + i) * R + r0 + tx] = (_Float16)tile[tx][i];
}

// W2 [2048][6272] f32 -> w2t_perm [6656][2048] f16
__global__ void k_transpose_perm(const float* __restrict__ in, _Float16* __restrict__ out) {
  __shared__ float tile[32][33];
  int c0 = blockIdx.x * 32, r0 = blockIdx.y * 32;
  int tx = threadIdx.x;
  for (int i = threadIdx.y; i < 32; i += 8)
    tile[i][tx] = in[(size_t)(r0 + i) * NCOL + c0 + tx];
  __syncthreads();
  for (int i = threadIdx.y; i < 32; i += 8) {
    int g = c0 + i;
    int t = g / 245;
    int cc = g - t * 245;
    out[(size_t)(t * 256 + cc) * HDIM + r0 + tx] = (_Float16)tile[tx][i];
  }
}

// ---------------- GEMM1: m97 128^2 structure (relu, f16 out) ----------------
__global__ __launch_bounds__(256) void k_gemm1(
    const _Float16* __restrict__ A, const _Float16* __restrict__ Bt,
    const float* __restrict__ bias, _Float16* __restrict__ C,
    int M, int N, int K) {
  __shared__ _Float16 Abuf[128 * 32];
  __shared__ _Float16 Bbuf[128 * 32];
  const int t = threadIdx.x;
  const int l = t & 63;
  const int w = t >> 6;
  int bx = blockIdx.x, by = blockIdx.y;
  {
    const int nx = gridDim.x;
    const int nwg = nx * gridDim.y;
    const int lin = by * nx + bx;
    const int cpx = nwg >> 3;
    const int sw = (lin & 7) * cpx + (lin >> 3);
    bx = sw % nx;
    by = sw / nx;
  }
  const int tileM = by * 128;
  const int tileN = bx * 128;
  const int wm = w >> 1, wn = w & 1;
  const int srow = w * 16 + (l >> 2);
  const int skel = (l & 3) * 8;
  const char* Ag = (const char*)(A + (size_t)(tileM + srow) * K + skel);
  const char* Bg = (const char*)(Bt + (size_t)(tileN + srow) * K + skel);
  const size_t gRowStep = (size_t)64 * K * 2;
  auto ldsA = (__attribute__((address_space(3))) char*)Abuf;
  auto ldsB = (__attribute__((address_space(3))) char*)Bbuf;
  const int ldsBase = w * 1024;
  f32x4 acc[4][4];
#pragma unroll
  for (int i = 0; i < 4; ++i)
#pragma unroll
    for (int j = 0; j < 4; ++j) acc[i][j] = (f32x4){0.f, 0.f, 0.f, 0.f};
  const int nk = K >> 5;
#define STAGE1(kt)                                                                             \
  do {                                                                                         \
    size_t koff = (size_t)(kt) * 64;                                                           \
    __builtin_amdgcn_global_load_lds(                                                          \
        (const __attribute__((address_space(1))) uint32_t*)(Ag + koff),                        \
        (__attribute__((address_space(3))) uint32_t*)(ldsA + ldsBase), 16, 0, 0);              \
    __builtin_amdgcn_global_load_lds(                                                          \
        (const __attribute__((address_space(1))) uint32_t*)(Ag + koff + gRowStep),             \
        (__attribute__((address_space(3))) uint32_t*)(ldsA + 4096 + ldsBase), 16, 0, 0);       \
    __builtin_amdgcn_global_load_lds(                                                          \
        (const __attribute__((address_space(1))) uint32_t*)(Bg + koff),                        \
        (__attribute__((address_space(3))) uint32_t*)(ldsB + ldsBase), 16, 0, 0);              \
    __builtin_amdgcn_global_load_lds(                                                          \
        (const __attribute__((address_space(1))) uint32_t*)(Bg + koff + gRowStep),             \
        (__attribute__((address_space(3))) uint32_t*)(ldsB + 4096 + ldsBase), 16, 0, 0);       \
  } while (0)
  STAGE1(0);
  const int abase = (wm * 64 + (l & 15)) * 32 + (l >> 4) * 8;
  const int bbase = (wn * 64 + (l & 15)) * 32 + (l >> 4) * 8;
  for (int kt = 0; kt < nk; ++kt) {
    __syncthreads();
    half8v av[4], bv[4];
#pragma unroll
    for (int mf = 0; mf < 4; ++mf)
      av[mf] = *(const half8v*)((const _Float16*)Abuf + abase + mf * 512);
#pragma unroll
    for (int nf = 0; nf < 4; ++nf)
      bv[nf] = *(const half8v*)((const _Float16*)Bbuf + bbase + nf * 512);
#pragma unroll
    for (int mf = 0; mf < 4; ++mf)
#pragma unroll
      for (int nf = 0; nf < 4; ++nf)
        acc[mf][nf] = __builtin_amdgcn_mfma_f32_16x16x32_f16(av[mf], bv[nf], acc[mf][nf], 0, 0, 0);
    __syncthreads();
    if (kt + 1 < nk) STAGE1(kt + 1);
  }
#undef STAGE1
  const int crow0 = tileM + wm * 64 + (l >> 4) * 4;
  const int ccol0 = tileN + wn * 64 + (l & 15);
#pragma unroll
  for (int nf = 0; nf < 4; ++nf) {
    const int col = ccol0 + nf * 16;
    const float bvv = bias[col];
#pragma unroll
    for (int mf = 0; mf < 4; ++mf) {
#pragma unroll
      for (int j = 0; j < 4; ++j) {
        const int row = crow0 + mf * 16 + j;
        float v = fmaxf(acc[mf][nf][j] + bvv, 0.f);
        C[(size_t)row * N + col] = (_Float16)v;
      }
    }
  }
}

// ---------------- GEMM2 + fused spline epilogue -----------------------------
// K-loop: round-5 verified stage/vmcnt/barrier schedule + A-read-ahead pipeline:
// each phase issues the NEXT quadrant's 4 ds_read_b128 (alternating reg sets)
// after barrier-A, then MFMAs the current quadrant -> A-read transfer overlaps
// the MFMA window (was strictly alternating -> 41% MfmaUtil ceiling).
__global__ __launch_bounds__(512, 2) void k_gemm2s(
    const _Float16* __restrict__ A, const _Float16* __restrict__ Bt,
    const float* __restrict__ bias, const float* __restrict__ y,
    float* __restrict__ outp, float* __restrict__ gpart, int M) {
  constexpr int K = HDIM;       // 2048
  constexpr int K2 = K * 2;     // row bytes
  constexpr int NT = K / 64;    // 32 K-tiles
  constexpr int ITERS = NT / 2; // 16

  __shared__ char smem[131072];
  __shared__ float red[512];

  const int t = threadIdx.x;
  const int l = t & 63;
  const int w = t >> 6;
  const int wm = w >> 2;
  const int wn = w & 3;
  const int rlo = l & 15;
  const int khi = l >> 4;
  const int wOff = w * 1024;

  // XCD mapping: each XCD owns 8 contiguous by rows, iterates bx-major
  int bx = blockIdx.x, by = blockIdx.y;   // 26 x 64
  {
    const int lin = by * 26 + bx;
    const int xcd = lin & 7;
    const int slot = lin >> 3;
    bx = slot >> 3;
    by = xcd * 8 + (slot & 7);
  }
  const int tileM = by * 256;
  const int tileN = bx * 256;

  // staging source decode: LDS phys -> logical (involution: bit9 -> bit5)
  int rowj[2], kbj[2];
#pragma unroll
  for (int j = 0; j < 2; ++j) {
    const int phys = j * 8192 + t * 16;
    const int b = phys ^ (((phys >> 9) & 1) << 5);
    rowj[j] = ((b >> 11) << 4) + ((b >> 6) & 15);
    kbj[j] = (((b >> 10) & 1) << 6) + (b & 63);
  }
  const char* pA[2][2];
  const char* pB[2][2];
#pragma unroll
  for (int half = 0; half < 2; ++half)
#pragma unroll
    for (int j = 0; j < 2; ++j) {
      pA[half][j] = (const char*)A + (size_t)(tileM + half * 128 + rowj[j]) * K2 + kbj[j];
      pB[half][j] = (const char*)Bt + (size_t)(tileN + half * 128 + rowj[j]) * K2 + kbj[j];
    }

  auto lds3 = (__attribute__((address_space(3))) char*)smem;

#define LDSA(d, half) ((d) * 32768 + (half) * 16384)
#define LDSB(d, half) (65536 + (d) * 32768 + (half) * 16384)
#define GLDS(srcp, ldsoff)                                                                   \
  __builtin_amdgcn_global_load_lds(                                                           \
      (const __attribute__((address_space(1))) uint32_t*)(srcp),                              \
      (__attribute__((address_space(3))) uint32_t*)(lds3 + (ldsoff) + wOff), 16, 0, 0)
#define STG(op, d, half, kt)                                                                  \
  do {                                                                                        \
    GLDS(p##op[half][0] + (size_t)(kt) * 128, LDS##op(d, half));                              \
    GLDS(p##op[half][1] + (size_t)(kt) * 128, LDS##op(d, half) + 8192);                       \
  } while (0)
#define VM(n) asm volatile("s_waitcnt vmcnt(" #n ")" ::: "memory")
#define NOSTG ((void)0)
#define NOW ((void)0)
#define NORD ((void)0)
#define CFENCE asm volatile("" ::: "memory")

  const int swz = (rlo & 8) ? 32 : 0;
  const int lane16 = rlo * 64 + ((khi * 16) ^ swz);
  const int aW = wm * 8192 + lane16;
  const int bW = 65536 + wn * 4096 + lane16;

  // B fragments (single set; reloaded at q0-phase headers)
  half8v b000, b001, b010, b011, b100, b101, b110, b111;
  // A fragments, double-buffered sets s0/s1 (read-ahead pipeline)
  half8v s0_0, s0_1, s0_2, s0_3;
  half8v s1_0, s1_1, s1_2, s1_3;

  f32x4 acc[8][4];
#pragma unroll
  for (int i = 0; i < 8; ++i)
#pragma unroll
    for (int j = 0; j < 4; ++j) acc[i][j] = (f32x4){0.f, 0.f, 0.f, 0.f};

#define MF(fi, gj, av, bv) \
  acc[fi][gj] = __builtin_amdgcn_mfma_f32_16x16x32_f16(av, bv, acc[fi][gj], 0, 0, 0)

// issue the 4 A-reads of buffer d, quadrant q into set S (plain loads;
// compiler inserts the staggered lgkmcnt before first consuming MFMA)
#define RDA(S, d, q)                                                                          \
  do {                                                                                        \
    const int aB = (d) * 32768 + ((q) >> 1) * 16384 + ((q) & 1) * 4096 + aW;                  \
    S##_0 = *(const half8v*)(smem + aB);                                                      \
    S##_1 = *(const half8v*)(smem + aB + 1024);                                               \
    S##_2 = *(const half8v*)(smem + aB + 2048);                                               \
    S##_3 = *(const half8v*)(smem + aB + 3072);                                               \
  } while (0)

#define HDRB(d)                                                                               \
  do {                                                                                        \
    const int bB = (d) * 32768 + bW;                                                          \
    b000 = *(const half8v*)(smem + bB);                                                       \
    b001 = *(const half8v*)(smem + bB + 1024);                                                \
    b010 = *(const half8v*)(smem + bB + 2048);                                                \
    b011 = *(const half8v*)(smem + bB + 3072);                                                \
    b100 = *(const half8v*)(smem + bB + 16384);                                               \
    b101 = *(const half8v*)(smem + bB + 17408);                                               \
    b110 = *(const half8v*)(smem + bB + 18432);                                               \
    b111 = *(const half8v*)(smem + bB + 19456);                                               \
  } while (0)

// 16 MFMAs of quadrant q from set S (8 independent, then dependent partners)
#define MFQ(q, S)                                                                             \
  {                                                                                           \
    constexpr int f0 = ((q) >> 1) * 4 + ((q) & 1) * 2;                                        \
    MF(f0 + 0, 0, S##_0, b000); MF(f0 + 0, 1, S##_0, b010);                                   \
    MF(f0 + 0, 2, S##_0, b100); MF(f0 + 0, 3, S##_0, b110);                                   \
    MF(f0 + 1, 0, S##_2, b000); MF(f0 + 1, 1, S##_2, b010);                                   \
    MF(f0 + 1, 2, S##_2, b100); MF(f0 + 1, 3, S##_2, b110);                                   \
    MF(f0 + 0, 0, S##_1, b001); MF(f0 + 0, 1, S##_1, b011);                                   \
    MF(f0 + 0, 2, S##_1, b101); MF(f0 + 0, 3, S##_1, b111);                                   \
    MF(f0 + 1, 0, S##_3, b001); MF(f0 + 1, 1, S##_3, b011);                                   \
    MF(f0 + 1, 2, S##_3, b101); MF(f0 + 1, 3, S##_3, b111);                                   \
  }

// phase: [header stages/B-reload]; [vmcnt]; barrier; [read-ahead next quadrant];
// setprio; MFMA current quadrant; setprio; barrier.
#define PH2(STAGES, WAITS, RD, MFMAS)                                                         \
  do {                                                                                        \
    STAGES;                                                                                   \
    WAITS;                                                                                    \
    CFENCE;                                                                                   \
    __builtin_amdgcn_s_barrier();                                                             \
    CFENCE;                                                                                   \
    RD;                                                                                       \
    __builtin_amdgcn_s_setprio(1);                                                            \
    MFMAS;                                                                                    \
    __builtin_amdgcn_s_setprio(0);                                                            \
    CFENCE;                                                                                   \
    __builtin_amdgcn_s_barrier();                                                             \
  } while (0)

  // prologue: tile0 full -> buf0; tile1 B+A-h0 -> buf1; then prime s0 with q0
  STG(B, 0, 0, 0);
  STG(B, 0, 1, 0);
  STG(A, 0, 0, 0);
  STG(A, 0, 1, 0);
  STG(B, 1, 0, 1);
  STG(B, 1, 1, 1);
  STG(A, 1, 0, 1);
  VM(6);
  CFENCE;
  __builtin_amdgcn_s_barrier();
  RDA(s0, 0, 0);

  // steady state: tiles kt (buf0) ph1-4, kt+1 (buf1) ph5-8.
  // In-flight ledger identical to round-5 (stages/VM unchanged); read-ahead:
  //   ph4 reads buf1-q0 (needs e,f drained: VM(8) here),
  //   ph6 reads buf1-q2 (needs a drained: VM(10) here),
  //   ph8 reads next-buf0-q0 (needs b,c,d drained: VM(6) here).
  for (int it = 0; it < ITERS - 1; ++it) {
    const int kt = 2 * it;
    PH2(HDRB(0); STG(A, 1, 1, kt + 1), NOW, RDA(s1, 0, 1), MFQ(0, s0));
    PH2(STG(B, 0, 0, kt + 2), NOW, RDA(s0, 0, 2), MFQ(1, s1));
    PH2(STG(B, 0, 1, kt + 2); STG(A, 0, 0, kt + 2), NOW, RDA(s1, 0, 3), MFQ(2, s0));
    PH2(NOSTG, VM(8), RDA(s0, 1, 0), MFQ(3, s1));
    PH2(HDRB(1); STG(A, 0, 1, kt + 2), NOW, RDA(s1, 1, 1), MFQ(0, s0));
    PH2(STG(B, 1, 0, kt + 3), VM(10), RDA(s0, 1, 2), MFQ(1, s1));
    PH2(STG(B, 1, 1, kt + 3); STG(A, 1, 0, kt + 3), NOW, RDA(s1, 1, 3), MFQ(2, s0));
    PH2(NOSTG, VM(6), RDA(s0, 0, 0), MFQ(3, s1));
  }
  // tail: tiles NT-2 (buf0), NT-1 (buf1); only A(b1,h1,NT-1) left to stage
  PH2(HDRB(0); STG(A, 1, 1, NT - 1), NOW, RDA(s1, 0, 1), MFQ(0, s0));
  PH2(NOSTG, NOW, RDA(s0, 0, 2), MFQ(1, s1));
  PH2(NOSTG, NOW, RDA(s1, 0, 3), MFQ(2, s0));
  PH2(NOSTG, VM(2), RDA(s0, 1, 0), MFQ(3, s1));
  PH2(HDRB(1), NOW, RDA(s1, 1, 1), MFQ(0, s0));
  PH2(NOSTG, VM(0), RDA(s0, 1, 2), MFQ(1, s1));
  PH2(NOSTG, NOW, RDA(s1, 1, 3), MFQ(2, s0));
  PH2(NOSTG, NOW, NORD, MFQ(3, s1));

#undef PH2
#undef MFQ
#undef HDRB
#undef RDA
#undef MF
#undef STG
#undef GLDS
#undef LDSA
#undef LDSB

  // ---- fused epilogue ------------------------------------------------------
  const int RCt = (bx < 25) ? 245 : 147;
  const int nd  = (bx < 25) ? 5 : 3;

  // C-tile -> LDS col-major: addr(c,r) = c*512 + ((2r) ^ ((c&31)<<4))
#pragma unroll
  for (int fi = 0; fi < 8; ++fi) {
    const int r0l = (((fi >> 2) * 2 + wm) << 6) + ((fi & 3) << 4) + khi * 4;
#pragma unroll
    for (int gj = 0; gj < 4; ++gj) {
      const int c = (((gj >> 1) * 4 + wn) << 5) + ((gj & 1) << 4) + rlo;
      if (c < RCt) {
        const float bvv = bias[245 * bx + c];
        const int cb = c * 512;
        const int cs = (c & 31) << 4;
#pragma unroll
        for (int jp = 0; jp < 2; ++jp) {
          const int r = r0l + jp * 2;
          const unsigned short lo =
              __builtin_bit_cast(unsigned short, (_Float16)(acc[fi][gj][jp * 2] + bvv));
          const unsigned short hi =
              __builtin_bit_cast(unsigned short, (_Float16)(acc[fi][gj][jp * 2 + 1] + bvv));
          *(uint32_t*)(smem + cb + ((2 * r) ^ cs)) = (uint32_t)lo | ((uint32_t)hi << 16);
        }
      }
    }
  }
  __syncthreads();

  // spline: row r = t&255; dim d = pass*2 + (t>>8)
  const int r = t & 255;
  const int rg = tileM + r;
  float yv_[3];
#pragma unroll
  for (int pass = 0; pass < 3; ++pass) {
    const int d = pass * 2 + (t >> 8);
    yv_[pass] = (d < nd) ? y[(size_t)rg * DYDIM + 5 * bx + d] : 0.f;
  }

#define LDC(p) ((float)*(const _Float16*)(smem + (size_t)(dD * 49 + (p)) * 512 + \
                                          ((2 * r) ^ (((dD * 49 + (p)) & 31) << 4))))
  float lsum = 0.f;
#pragma unroll
  for (int pass = 0; pass < 3; ++pass) {
    const int dD = pass * 2 + (t >> 8);
    if (dD < nd) {
      float qw[16], qh[16], qd[17];
#pragma unroll
      for (int p = 0; p < 16; ++p) { qw[p] = LDC(p); qh[p] = LDC(16 + p); }
#pragma unroll
      for (int p = 0; p < 17; ++p) qd[p] = LDC(32 + p);

      float mw = qw[0], mh = qh[0];
#pragma unroll
      for (int p = 1; p < 16; ++p) { mw = fmaxf(mw, qw[p]); mh = fmaxf(mh, qh[p]); }
      float ew[16], eh[16];
      float sw2 = 0.f, sh = 0.f;
#pragma unroll
      for (int p = 0; p < 16; ++p) {
        ew[p] = __expf(qw[p] - mw);
        eh[p] = __expf(qh[p] - mh);
        sw2 += ew[p];
        sh += eh[p];
      }
      const float rw = 0.984f / sw2, rh = 0.984f / sh;
      const float yv = yv_[pass];

      float cws = 0.f, chs = 0.f, xk = 0.f, yk = 0.f, wk = 1.f, hk = 1.f;
      float du0 = qd[0], du1 = qd[1];
#pragma unroll
      for (int j = 0; j < 16; ++j) {
        float wj = 0.001f + rw * ew[j];
        float hj = 0.001f + rh * eh[j];
        if (yv >= cws) { xk = cws; yk = chs; wk = wj; hk = hj; du0 = qd[j]; du1 = qd[j + 1]; }
        cws += wj;
        chs += hj;
      }
      const float dk  = 0.001f + fmaxf(du0, 0.f) + log1pf(__expf(-fabsf(du0)));
      const float dk1 = 0.001f + fmaxf(du1, 0.f) + log1pf(__expf(-fabsf(du1)));

      const float s = hk / wk;
      const float tt = (yv - xk) / wk;
      const float omt = 1.f - tt;
      const float dnm = s + (dk1 + dk - 2.f * s) * tt * omt;
      const float o = yk + hk * (s * tt * tt + dk * tt * omt) / dnm;
      const float dr = s * s * (dk1 * tt * tt + 2.f * s * tt * omt + dk * omt * omt) / (dnm * dnm);

      outp[(size_t)rg * DYDIM + 5 * bx + dD] = o;
      lsum += __logf(dr);
    }
  }
#undef LDC
  red[t] = lsum;
  __syncthreads();
  if (t < 256)
    gpart[(size_t)bx * B_ROWS + (tileM + t)] = red[t] + red[t + 256];
}

// ---------------- dlogp reduce ----------------
__global__ void k_dlogp_reduce(const float* __restrict__ gpart, float* __restrict__ dlogp) {
  int b = blockIdx.x * 256 + threadIdx.x;
  float s = 0.f;
  for (int tt = 0; tt < NTILES; ++tt) s += gpart[(size_t)tt * B_ROWS + b];
  dlogp[b] = s;
}

// ---------------- launch ----------------
extern "C" void kernel_launch(void* const* d_in, const int* in_sizes, int n_in,
                              void* d_out, int out_size, void* d_ws, size_t ws_size,
                              hipStream_t stream) {
  const float* x  = (const float*)d_in[0];
  const float* y  = (const float*)d_in[1];
  const float* W1 = (const float*)d_in[2];
  const float* b1 = (const float*)d_in[3];
  const float* W2 = (const float*)d_in[4];
  const float* b2 = (const float*)d_in[5];
  float* out = (float*)d_out;
  float* dlogp = out + (size_t)B_ROWS * DYDIM;

  char* ws = (char*)d_ws;
  _Float16* w2p = (_Float16*)ws;
  _Float16* h   = w2p + (size_t)W2PROWS * HDIM;
  _Float16* xb  = h + (size_t)B_ROWS * HDIM;
  _Float16* w1t = xb + (size_t)B_ROWS * DX;
  float* gpart  = (float*)(w1t + (size_t)HDIM * DX);

  k_f32_to_f16<<<(B_ROWS * DX + 255) / 256, 256, 0, stream>>>(x, xb, B_ROWS * DX);
  k_transpose_f16<<<dim3(HDIM / 32, DX / 32), dim3(32, 8), 0, stream>>>(W1, w1t, DX, HDIM);
  k_transpose_perm<<<dim3(NCOL / 32, HDIM / 32), dim3(32, 8), 0, stream>>>(W2, w2p);

  k_gemm1<<<dim3(HDIM / 128, B_ROWS / 128), 256, 0, stream>>>(
      xb, w1t, b1, h, B_ROWS, HDIM, DX);

  k_gemm2s<<<dim3(NTILES, B_ROWS / 256), 512, 0, stream>>>(
      h, w2p, b2, y, out, gpart, B_ROWS);

  k_dlogp_reduce<<<B_ROWS / 256, 256, 0, stream>>>(gpart, dlogp);
}

// Round 10
// 489.109 us; speedup vs baseline: 1.1193x; 1.1193x over previous
//
#include <hip/hip_runtime.h>
#include <hip/hip_fp16.h>
#include <cstdint>
#include <cstddef>

#define B_ROWS 16384
#define DX 128
#define DYDIM 128
#define HDIM 2048
#define NPARAM 49              // 3K+1
#define NCOL 6272              // DYDIM*NPARAM
#define NTILES 26              // ceil(128 dims / 5 dims-per-tile)
#define W2PROWS (NTILES * 256) // 6656 permuted W2 rows

typedef __attribute__((ext_vector_type(8))) _Float16 half8v;
typedef __attribute__((ext_vector_type(4))) float f32x4;

// ---------------- prep kernels ----------------
__global__ void k_f32_to_f16(const float* __restrict__ in, _Float16* __restrict__ out, int n) {
  int i = blockIdx.x * 256 + threadIdx.x;
  if (i < n) out[i] = (_Float16)in[i];
}

__global__ void k_transpose_f16(const float* __restrict__ in, _Float16* __restrict__ out, int R, int C) {
  __shared__ float tile[32][33];
  int c0 = blockIdx.x * 32, r0 = blockIdx.y * 32;
  int tx = threadIdx.x;
  for (int i = threadIdx.y; i < 32; i += 8)
    tile[i][tx] = in[(size_t)(r0 + i) * C + c0 + tx];
  __syncthreads();
  for (int i = threadIdx.y; i < 32; i += 8)
    out[(size_t)(c0 + i) * R + r0 + tx] = (_Float16)tile[tx][i];
}

// W2 [2048][6272] f32 -> w2t_perm [6656][2048] f16
__global__ void k_transpose_perm(const float* __restrict__ in, _Float16* __restrict__ out) {
  __shared__ float tile[32][33];
  int c0 = blockIdx.x * 32, r0 = blockIdx.y * 32;
  int tx = threadIdx.x;
  for (int i = threadIdx.y; i < 32; i += 8)
    tile[i][tx] = in[(size_t)(r0 + i) * NCOL + c0 + tx];
  __syncthreads();
  for (int i = threadIdx.y; i < 32; i += 8) {
    int g = c0 + i;
    int t = g / 245;
    int cc = g - t * 245;
    out[(size_t)(t * 256 + cc) * HDIM + r0 + tx] = (_Float16)tile[tx][i];
  }
}

// ---------------- GEMM1: m97 128^2 structure (relu, f16 out) ----------------
__global__ __launch_bounds__(256) void k_gemm1(
    const _Float16* __restrict__ A, const _Float16* __restrict__ Bt,
    const float* __restrict__ bias, _Float16* __restrict__ C,
    int M, int N, int K) {
  __shared__ _Float16 Abuf[128 * 32];
  __shared__ _Float16 Bbuf[128 * 32];
  const int t = threadIdx.x;
  const int l = t & 63;
  const int w = t >> 6;
  int bx = blockIdx.x, by = blockIdx.y;
  {
    const int nx = gridDim.x;
    const int nwg = nx * gridDim.y;
    const int lin = by * nx + bx;
    const int cpx = nwg >> 3;
    const int sw = (lin & 7) * cpx + (lin >> 3);
    bx = sw % nx;
    by = sw / nx;
  }
  const int tileM = by * 128;
  const int tileN = bx * 128;
  const int wm = w >> 1, wn = w & 1;
  const int srow = w * 16 + (l >> 2);
  const int skel = (l & 3) * 8;
  const char* Ag = (const char*)(A + (size_t)(tileM + srow) * K + skel);
  const char* Bg = (const char*)(Bt + (size_t)(tileN + srow) * K + skel);
  const size_t gRowStep = (size_t)64 * K * 2;
  auto ldsA = (__attribute__((address_space(3))) char*)Abuf;
  auto ldsB = (__attribute__((address_space(3))) char*)Bbuf;
  const int ldsBase = w * 1024;
  f32x4 acc[4][4];
#pragma unroll
  for (int i = 0; i < 4; ++i)
#pragma unroll
    for (int j = 0; j < 4; ++j) acc[i][j] = (f32x4){0.f, 0.f, 0.f, 0.f};
  const int nk = K >> 5;
#define STAGE1(kt)                                                                             \
  do {                                                                                         \
    size_t koff = (size_t)(kt) * 64;                                                           \
    __builtin_amdgcn_global_load_lds(                                                          \
        (const __attribute__((address_space(1))) uint32_t*)(Ag + koff),                        \
        (__attribute__((address_space(3))) uint32_t*)(ldsA + ldsBase), 16, 0, 0);              \
    __builtin_amdgcn_global_load_lds(                                                          \
        (const __attribute__((address_space(1))) uint32_t*)(Ag + koff + gRowStep),             \
        (__attribute__((address_space(3))) uint32_t*)(ldsA + 4096 + ldsBase), 16, 0, 0);       \
    __builtin_amdgcn_global_load_lds(                                                          \
        (const __attribute__((address_space(1))) uint32_t*)(Bg + koff),                        \
        (__attribute__((address_space(3))) uint32_t*)(ldsB + ldsBase), 16, 0, 0);              \
    __builtin_amdgcn_global_load_lds(                                                          \
        (const __attribute__((address_space(1))) uint32_t*)(Bg + koff + gRowStep),             \
        (__attribute__((address_space(3))) uint32_t*)(ldsB + 4096 + ldsBase), 16, 0, 0);       \
  } while (0)
  STAGE1(0);
  const int abase = (wm * 64 + (l & 15)) * 32 + (l >> 4) * 8;
  const int bbase = (wn * 64 + (l & 15)) * 32 + (l >> 4) * 8;
  for (int kt = 0; kt < nk; ++kt) {
    __syncthreads();
    half8v av[4], bv[4];
#pragma unroll
    for (int mf = 0; mf < 4; ++mf)
      av[mf] = *(const half8v*)((const _Float16*)Abuf + abase + mf * 512);
#pragma unroll
    for (int nf = 0; nf < 4; ++nf)
      bv[nf] = *(const half8v*)((const _Float16*)Bbuf + bbase + nf * 512);
#pragma unroll
    for (int mf = 0; mf < 4; ++mf)
#pragma unroll
      for (int nf = 0; nf < 4; ++nf)
        acc[mf][nf] = __builtin_amdgcn_mfma_f32_16x16x32_f16(av[mf], bv[nf], acc[mf][nf], 0, 0, 0);
    __syncthreads();
    if (kt + 1 < nk) STAGE1(kt + 1);
  }
#undef STAGE1
  const int crow0 = tileM + wm * 64 + (l >> 4) * 4;
  const int ccol0 = tileN + wn * 64 + (l & 15);
#pragma unroll
  for (int nf = 0; nf < 4; ++nf) {
    const int col = ccol0 + nf * 16;
    const float bvv = bias[col];
#pragma unroll
    for (int mf = 0; mf < 4; ++mf) {
#pragma unroll
      for (int j = 0; j < 4; ++j) {
        const int row = crow0 + mf * 16 + j;
        float v = fmaxf(acc[mf][nf][j] + bvv, 0.f);
        C[(size_t)row * N + col] = (_Float16)v;
      }
    }
  }
}

// ---------------- GEMM2 + fused spline epilogue -----------------------------
// K-loop: round-8 verified stage/vmcnt ledger, phases merged pairwise into
// 4 regions/iter (8 barriers vs 16). Region: {read qa (+B hdr); stages; wait;
// barrier; MFQ(qa); read qb (drains under qa's MFMAs); MFQ(qb); barrier}.
__global__ __launch_bounds__(512, 2) void k_gemm2s(
    const _Float16* __restrict__ A, const _Float16* __restrict__ Bt,
    const float* __restrict__ bias, const float* __restrict__ y,
    float* __restrict__ outp, float* __restrict__ gpart, int M) {
  constexpr int K = HDIM;       // 2048
  constexpr int K2 = K * 2;     // row bytes
  constexpr int NT = K / 64;    // 32 K-tiles
  constexpr int ITERS = NT / 2; // 16

  __shared__ char smem[131072];
  __shared__ float red[512];

  const int t = threadIdx.x;
  const int l = t & 63;
  const int w = t >> 6;
  const int wm = w >> 2;
  const int wn = w & 3;
  const int rlo = l & 15;
  const int khi = l >> 4;
  const int wOff = w * 1024;

  // XCD mapping: each XCD owns 8 contiguous by rows, iterates bx-major
  int bx = blockIdx.x, by = blockIdx.y;   // 26 x 64
  {
    const int lin = by * 26 + bx;
    const int xcd = lin & 7;
    const int slot = lin >> 3;
    bx = slot >> 3;
    by = xcd * 8 + (slot & 7);
  }
  const int tileM = by * 256;
  const int tileN = bx * 256;

  // staging source decode: LDS phys -> logical (involution: bit9 -> bit5)
  int rowj[2], kbj[2];
#pragma unroll
  for (int j = 0; j < 2; ++j) {
    const int phys = j * 8192 + t * 16;
    const int b = phys ^ (((phys >> 9) & 1) << 5);
    rowj[j] = ((b >> 11) << 4) + ((b >> 6) & 15);
    kbj[j] = (((b >> 10) & 1) << 6) + (b & 63);
  }
  const char* pA[2][2];
  const char* pB[2][2];
#pragma unroll
  for (int half = 0; half < 2; ++half)
#pragma unroll
    for (int j = 0; j < 2; ++j) {
      pA[half][j] = (const char*)A + (size_t)(tileM + half * 128 + rowj[j]) * K2 + kbj[j];
      pB[half][j] = (const char*)Bt + (size_t)(tileN + half * 128 + rowj[j]) * K2 + kbj[j];
    }

  auto lds3 = (__attribute__((address_space(3))) char*)smem;

#define LDSA(d, half) ((d) * 32768 + (half) * 16384)
#define LDSB(d, half) (65536 + (d) * 32768 + (half) * 16384)
#define GLDS(srcp, ldsoff)                                                                   \
  __builtin_amdgcn_global_load_lds(                                                           \
      (const __attribute__((address_space(1))) uint32_t*)(srcp),                              \
      (__attribute__((address_space(3))) uint32_t*)(lds3 + (ldsoff) + wOff), 16, 0, 0)
#define STG(op, d, half, kt)                                                                  \
  do {                                                                                        \
    GLDS(p##op[half][0] + (size_t)(kt) * 128, LDS##op(d, half));                              \
    GLDS(p##op[half][1] + (size_t)(kt) * 128, LDS##op(d, half) + 8192);                       \
  } while (0)
#define VM(n) asm volatile("s_waitcnt vmcnt(" #n ")" ::: "memory")
#define NOSTG ((void)0)
#define NOW ((void)0)
#define CFENCE asm volatile("" ::: "memory")

  const int swz = (rlo & 8) ? 32 : 0;
  const int lane16 = rlo * 64 + ((khi * 16) ^ swz);
  const int aW = wm * 8192 + lane16;
  const int bW = 65536 + wn * 4096 + lane16;

  half8v b000, b001, b010, b011, b100, b101, b110, b111;
  f32x4 acc[8][4];
#pragma unroll
  for (int i = 0; i < 8; ++i)
#pragma unroll
    for (int j = 0; j < 4; ++j) acc[i][j] = (f32x4){0.f, 0.f, 0.f, 0.f};

#define MF(fi, gj, av, bv) \
  acc[fi][gj] = __builtin_amdgcn_mfma_f32_16x16x32_f16(av, bv, acc[fi][gj], 0, 0, 0)

#define RD4(v0, v1, v2, v3, d, q)                                                             \
  do {                                                                                        \
    const int aB = (d) * 32768 + ((q) >> 1) * 16384 + ((q) & 1) * 4096 + aW;                  \
    v0 = *(const half8v*)(smem + aB);                                                         \
    v1 = *(const half8v*)(smem + aB + 1024);                                                  \
    v2 = *(const half8v*)(smem + aB + 2048);                                                  \
    v3 = *(const half8v*)(smem + aB + 3072);                                                  \
  } while (0)

#define HDRB(d)                                                                               \
  do {                                                                                        \
    const int bB = (d) * 32768 + bW;                                                          \
    b000 = *(const half8v*)(smem + bB);                                                       \
    b001 = *(const half8v*)(smem + bB + 1024);                                                \
    b010 = *(const half8v*)(smem + bB + 2048);                                                \
    b011 = *(const half8v*)(smem + bB + 3072);                                                \
    b100 = *(const half8v*)(smem + bB + 16384);                                               \
    b101 = *(const half8v*)(smem + bB + 17408);                                               \
    b110 = *(const half8v*)(smem + bB + 18432);                                               \
    b111 = *(const half8v*)(smem + bB + 19456);                                               \
  } while (0)

// 16 MFMAs of quadrant q (8 independent, then dependent partners)
#define MFQ4(q, v0, v1, v2, v3)                                                               \
  {                                                                                           \
    constexpr int f0 = ((q) >> 1) * 4 + ((q) & 1) * 2;                                        \
    MF(f0 + 0, 0, v0, b000); MF(f0 + 0, 1, v0, b010);                                         \
    MF(f0 + 0, 2, v0, b100); MF(f0 + 0, 3, v0, b110);                                         \
    MF(f0 + 1, 0, v2, b000); MF(f0 + 1, 1, v2, b010);                                         \
    MF(f0 + 1, 2, v2, b100); MF(f0 + 1, 3, v2, b110);                                         \
    MF(f0 + 0, 0, v1, b001); MF(f0 + 0, 1, v1, b011);                                         \
    MF(f0 + 0, 2, v1, b101); MF(f0 + 0, 3, v1, b111);                                         \
    MF(f0 + 1, 0, v3, b001); MF(f0 + 1, 1, v3, b011);                                         \
    MF(f0 + 1, 2, v3, b101); MF(f0 + 1, 3, v3, b111);                                         \
  }

// merged region: quadrants qa,qb of buffer d; HDR=1 reloads B (q0 regions)
#define REGION(d, HDR, qa, qb, STAGES, WAITS)                                                 \
  do {                                                                                        \
    half8v x0, x1, x2, x3, z0, z1, z2, z3;                                                    \
    RD4(x0, x1, x2, x3, d, qa);                                                               \
    if (HDR) HDRB(d);                                                                         \
    STAGES;                                                                                   \
    WAITS;                                                                                    \
    CFENCE;                                                                                   \
    __builtin_amdgcn_s_barrier();                                                             \
    CFENCE;                                                                                   \
    __builtin_amdgcn_s_setprio(1);                                                            \
    MFQ4(qa, x0, x1, x2, x3);                                                                 \
    __builtin_amdgcn_s_setprio(0);                                                            \
    RD4(z0, z1, z2, z3, d, qb);                                                               \
    __builtin_amdgcn_s_setprio(1);                                                            \
    MFQ4(qb, z0, z1, z2, z3);                                                                 \
    __builtin_amdgcn_s_setprio(0);                                                            \
    CFENCE;                                                                                   \
    __builtin_amdgcn_s_barrier();                                                             \
  } while (0)

  // prologue: tile0 full (8 loads) -> buf0; tile1 B+A-h0 (6 loads) -> buf1
  STG(B, 0, 0, 0);
  STG(B, 0, 1, 0);
  STG(A, 0, 0, 0);
  STG(A, 0, 1, 0);
  STG(B, 1, 0, 1);
  STG(B, 1, 1, 1);
  STG(A, 1, 0, 1);
  VM(6);
  CFENCE;
  __builtin_amdgcn_s_barrier();

  // steady state (ledger simulated from prologue; outstanding at each VM:
  // R2's VM(8) drains tile kt+1 B+A-h0; R3's VM(10) drains A(1,1,kt+1);
  // R4's VM(6) drains tile kt+2 B+A -> entry condition 6 restored).
  for (int it = 0; it < ITERS - 1; ++it) {
    const int kt = 2 * it;
    REGION(0, 1, 0, 1, STG(A, 1, 1, kt + 1); STG(B, 0, 0, kt + 2), NOW);
    REGION(0, 0, 2, 3, STG(B, 0, 1, kt + 2); STG(A, 0, 0, kt + 2), VM(8));
    REGION(1, 1, 0, 1, STG(A, 0, 1, kt + 2); STG(B, 1, 0, kt + 3), VM(10));
    REGION(1, 0, 2, 3, STG(B, 1, 1, kt + 3); STG(A, 1, 0, kt + 3), VM(6));
  }
  // tail: tiles NT-2 (buf0), NT-1 (buf1)
  REGION(0, 1, 0, 1, STG(A, 1, 1, NT - 1), NOW);
  REGION(0, 0, 2, 3, NOSTG, VM(2));
  REGION(1, 1, 0, 1, NOSTG, VM(0));
  REGION(1, 0, 2, 3, NOSTG, NOW);

#undef REGION
#undef MFQ4
#undef HDRB
#undef RD4
#undef MF
#undef STG
#undef GLDS
#undef LDSA
#undef LDSB

  // ---- fused epilogue (round-8 verified) -----------------------------------
  const int RCt = (bx < 25) ? 245 : 147;
  const int nd  = (bx < 25) ? 5 : 3;

  // C-tile -> LDS col-major: addr(c,r) = c*512 + ((2r) ^ ((c&31)<<4))
#pragma unroll
  for (int fi = 0; fi < 8; ++fi) {
    const int r0l = (((fi >> 2) * 2 + wm) << 6) + ((fi & 3) << 4) + khi * 4;
#pragma unroll
    for (int gj = 0; gj < 4; ++gj) {
      const int c = (((gj >> 1) * 4 + wn) << 5) + ((gj & 1) << 4) + rlo;
      if (c < RCt) {
        const float bvv = bias[245 * bx + c];
        const int cb = c * 512;
        const int cs = (c & 31) << 4;
#pragma unroll
        for (int jp = 0; jp < 2; ++jp) {
          const int r = r0l + jp * 2;
          const unsigned short lo =
              __builtin_bit_cast(unsigned short, (_Float16)(acc[fi][gj][jp * 2] + bvv));
          const unsigned short hi =
              __builtin_bit_cast(unsigned short, (_Float16)(acc[fi][gj][jp * 2 + 1] + bvv));
          *(uint32_t*)(smem + cb + ((2 * r) ^ cs)) = (uint32_t)lo | ((uint32_t)hi << 16);
        }
      }
    }
  }
  __syncthreads();

  // spline: row r = t&255; dim d = pass*2 + (t>>8)
  const int r = t & 255;
  const int rg = tileM + r;
  float yv_[3];
#pragma unroll
  for (int pass = 0; pass < 3; ++pass) {
    const int d = pass * 2 + (t >> 8);
    yv_[pass] = (d < nd) ? y[(size_t)rg * DYDIM + 5 * bx + d] : 0.f;
  }

#define LDC(p) ((float)*(const _Float16*)(smem + (size_t)(dD * 49 + (p)) * 512 + \
                                          ((2 * r) ^ (((dD * 49 + (p)) & 31) << 4))))
  float lsum = 0.f;
#pragma unroll
  for (int pass = 0; pass < 3; ++pass) {
    const int dD = pass * 2 + (t >> 8);
    if (dD < nd) {
      float qw[16], qh[16], qd[17];
#pragma unroll
      for (int p = 0; p < 16; ++p) { qw[p] = LDC(p); qh[p] = LDC(16 + p); }
#pragma unroll
      for (int p = 0; p < 17; ++p) qd[p] = LDC(32 + p);

      float mw = qw[0], mh = qh[0];
#pragma unroll
      for (int p = 1; p < 16; ++p) { mw = fmaxf(mw, qw[p]); mh = fmaxf(mh, qh[p]); }
      float ew[16], eh[16];
      float sw2 = 0.f, sh = 0.f;
#pragma unroll
      for (int p = 0; p < 16; ++p) {
        ew[p] = __expf(qw[p] - mw);
        eh[p] = __expf(qh[p] - mh);
        sw2 += ew[p];
        sh += eh[p];
      }
      const float rw = 0.984f / sw2, rh = 0.984f / sh;
      const float yv = yv_[pass];

      float cws = 0.f, chs = 0.f, xk = 0.f, yk = 0.f, wk = 1.f, hk = 1.f;
      float du0 = qd[0], du1 = qd[1];
#pragma unroll
      for (int j = 0; j < 16; ++j) {
        float wj = 0.001f + rw * ew[j];
        float hj = 0.001f + rh * eh[j];
        if (yv >= cws) { xk = cws; yk = chs; wk = wj; hk = hj; du0 = qd[j]; du1 = qd[j + 1]; }
        cws += wj;
        chs += hj;
      }
      const float dk  = 0.001f + fmaxf(du0, 0.f) + log1pf(__expf(-fabsf(du0)));
      const float dk1 = 0.001f + fmaxf(du1, 0.f) + log1pf(__expf(-fabsf(du1)));

      const float s = hk / wk;
      const float tt = (yv - xk) / wk;
      const float omt = 1.f - tt;
      const float dnm = s + (dk1 + dk - 2.f * s) * tt * omt;
      const float o = yk + hk * (s * tt * tt + dk * tt * omt) / dnm;
      const float dr = s * s * (dk1 * tt * tt + 2.f * s * tt * omt + dk * omt * omt) / (dnm * dnm);

      outp[(size_t)rg * DYDIM + 5 * bx + dD] = o;
      lsum += __logf(dr);
    }
  }
#undef LDC
  red[t] = lsum;
  __syncthreads();
  if (t < 256)
    gpart[(size_t)bx * B_ROWS + (tileM + t)] = red[t] + red[t + 256];
}

// ---------------- dlogp reduce ----------------
__global__ void k_dlogp_reduce(const float* __restrict__ gpart, float* __restrict__ dlogp) {
  int b = blockIdx.x * 256 + threadIdx.x;
  float s = 0.f;
  for (int tt = 0; tt < NTILES; ++tt) s += gpart[(size_t)tt * B_ROWS + b];
  dlogp[b] = s;
}

// ---------------- launch ----------------
extern "C" void kernel_launch(void* const* d_in, const int* in_sizes, int n_in,
                              void* d_out, int out_size, void* d_ws, size_t ws_size,
                              hipStream_t stream) {
  const float* x  = (const float*)d_in[0];
  const float* y  = (const float*)d_in[1];
  const float* W1 = (const float*)d_in[2];
  const float* b1 = (const float*)d_in[3];
  const float* W2 = (const float*)d_in[4];
  const float* b2 = (const float*)d_in[5];
  float* out = (float*)d_out;
  float* dlogp = out + (size_t)B_ROWS * DYDIM;

  char* ws = (char*)d_ws;
  _Float16* w2p = (_Float16*)ws;
  _Float16* h   = w2p + (size_t)W2PROWS * HDIM;
  _Float16* xb  = h + (size_t)B_ROWS * HDIM;
  _Float16* w1t = xb + (size_t)B_ROWS * DX;
  float* gpart  = (float*)(w1t + (size_t)HDIM * DX);

  k_f32_to_f16<<<(B_ROWS * DX + 255) / 256, 256, 0, stream>>>(x, xb, B_ROWS * DX);
  k_transpose_f16<<<dim3(HDIM / 32, DX / 32), dim3(32, 8), 0, stream>>>(W1, w1t, DX, HDIM);
  k_transpose_perm<<<dim3(NCOL / 32, HDIM / 32), dim3(32, 8), 0, stream>>>(W2, w2p);

  k_gemm1<<<dim3(HDIM / 128, B_ROWS / 128), 256, 0, stream>>>(
      xb, w1t, b1, h, B_ROWS, HDIM, DX);

  k_gemm2s<<<dim3(NTILES, B_ROWS / 256), 512, 0, stream>>>(
      h, w2p, b2, y, out, gpart, B_ROWS);

  k_dlogp_reduce<<<B_ROWS / 256, 256, 0, stream>>>(gpart, dlogp);
}

// Round 12
// 487.517 us; speedup vs baseline: 1.1229x; 1.0033x over previous
//
#include <hip/hip_runtime.h>
#include <hip/hip_fp16.h>
#include <cstdint>
#include <cstddef>

#define B_ROWS 16384
#define DX 128
#define DYDIM 128
#define HDIM 2048
#define NPARAM 49              // 3K+1
#define NCOL 6272              // DYDIM*NPARAM
#define NTILES 26              // ceil(128 dims / 5 dims-per-tile)
#define W2PROWS (NTILES * 256) // 6656 permuted W2 rows

typedef __attribute__((ext_vector_type(8))) _Float16 half8v;
typedef __attribute__((ext_vector_type(4))) float f32x4;

// ---------------- prep kernels ----------------
__global__ void k_f32_to_f16(const float* __restrict__ in, _Float16* __restrict__ out, int n) {
  int i = blockIdx.x * 256 + threadIdx.x;
  if (i < n) out[i] = (_Float16)in[i];
}

__global__ void k_transpose_f16(const float* __restrict__ in, _Float16* __restrict__ out, int R, int C) {
  __shared__ float tile[32][33];
  int c0 = blockIdx.x * 32, r0 = blockIdx.y * 32;
  int tx = threadIdx.x;
  for (int i = threadIdx.y; i < 32; i += 8)
    tile[i][tx] = in[(size_t)(r0 + i) * C + c0 + tx];
  __syncthreads();
  for (int i = threadIdx.y; i < 32; i += 8)
    out[(size_t)(c0 + i) * R + r0 + tx] = (_Float16)tile[tx][i];
}

// W2 [2048][6272] f32 -> w2t_perm [6656][2048] f16
__global__ void k_transpose_perm(const float* __restrict__ in, _Float16* __restrict__ out) {
  __shared__ float tile[32][33];
  int c0 = blockIdx.x * 32, r0 = blockIdx.y * 32;
  int tx = threadIdx.x;
  for (int i = threadIdx.y; i < 32; i += 8)
    tile[i][tx] = in[(size_t)(r0 + i) * NCOL + c0 + tx];
  __syncthreads();
  for (int i = threadIdx.y; i < 32; i += 8) {
    int g = c0 + i;
    int t = g / 245;
    int cc = g - t * 245;
    out[(size_t)(t * 256 + cc) * HDIM + r0 + tx] = (_Float16)tile[tx][i];
  }
}

// ---------------- GEMM1: m97 128^2 structure (relu, f16 out) ----------------
__global__ __launch_bounds__(256) void k_gemm1(
    const _Float16* __restrict__ A, const _Float16* __restrict__ Bt,
    const float* __restrict__ bias, _Float16* __restrict__ C,
    int M, int N, int K) {
  __shared__ _Float16 Abuf[128 * 32];
  __shared__ _Float16 Bbuf[128 * 32];
  const int t = threadIdx.x;
  const int l = t & 63;
  const int w = t >> 6;
  int bx = blockIdx.x, by = blockIdx.y;
  {
    const int nx = gridDim.x;
    const int nwg = nx * gridDim.y;
    const int lin = by * nx + bx;
    const int cpx = nwg >> 3;
    const int sw = (lin & 7) * cpx + (lin >> 3);
    bx = sw % nx;
    by = sw / nx;
  }
  const int tileM = by * 128;
  const int tileN = bx * 128;
  const int wm = w >> 1, wn = w & 1;
  const int srow = w * 16 + (l >> 2);
  const int skel = (l & 3) * 8;
  const char* Ag = (const char*)(A + (size_t)(tileM + srow) * K + skel);
  const char* Bg = (const char*)(Bt + (size_t)(tileN + srow) * K + skel);
  const size_t gRowStep = (size_t)64 * K * 2;
  auto ldsA = (__attribute__((address_space(3))) char*)Abuf;
  auto ldsB = (__attribute__((address_space(3))) char*)Bbuf;
  const int ldsBase = w * 1024;
  f32x4 acc[4][4];
#pragma unroll
  for (int i = 0; i < 4; ++i)
#pragma unroll
    for (int j = 0; j < 4; ++j) acc[i][j] = (f32x4){0.f, 0.f, 0.f, 0.f};
  const int nk = K >> 5;
#define STAGE1(kt)                                                                             \
  do {                                                                                         \
    size_t koff = (size_t)(kt) * 64;                                                           \
    __builtin_amdgcn_global_load_lds(                                                          \
        (const __attribute__((address_space(1))) uint32_t*)(Ag + koff),                        \
        (__attribute__((address_space(3))) uint32_t*)(ldsA + ldsBase), 16, 0, 0);              \
    __builtin_amdgcn_global_load_lds(                                                          \
        (const __attribute__((address_space(1))) uint32_t*)(Ag + koff + gRowStep),             \
        (__attribute__((address_space(3))) uint32_t*)(ldsA + 4096 + ldsBase), 16, 0, 0);       \
    __builtin_amdgcn_global_load_lds(                                                          \
        (const __attribute__((address_space(1))) uint32_t*)(Bg + koff),                        \
        (__attribute__((address_space(3))) uint32_t*)(ldsB + ldsBase), 16, 0, 0);              \
    __builtin_amdgcn_global_load_lds(                                                          \
        (const __attribute__((address_space(1))) uint32_t*)(Bg + koff + gRowStep),             \
        (__attribute__((address_space(3))) uint32_t*)(ldsB + 4096 + ldsBase), 16, 0, 0);       \
  } while (0)
  STAGE1(0);
  const int abase = (wm * 64 + (l & 15)) * 32 + (l >> 4) * 8;
  const int bbase = (wn * 64 + (l & 15)) * 32 + (l >> 4) * 8;
  for (int kt = 0; kt < nk; ++kt) {
    __syncthreads();
    half8v av[4], bv[4];
#pragma unroll
    for (int mf = 0; mf < 4; ++mf)
      av[mf] = *(const half8v*)((const _Float16*)Abuf + abase + mf * 512);
#pragma unroll
    for (int nf = 0; nf < 4; ++nf)
      bv[nf] = *(const half8v*)((const _Float16*)Bbuf + bbase + nf * 512);
#pragma unroll
    for (int mf = 0; mf < 4; ++mf)
#pragma unroll
      for (int nf = 0; nf < 4; ++nf)
        acc[mf][nf] = __builtin_amdgcn_mfma_f32_16x16x32_f16(av[mf], bv[nf], acc[mf][nf], 0, 0, 0);
    __syncthreads();
    if (kt + 1 < nk) STAGE1(kt + 1);
  }
#undef STAGE1
  const int crow0 = tileM + wm * 64 + (l >> 4) * 4;
  const int ccol0 = tileN + wn * 64 + (l & 15);
#pragma unroll
  for (int nf = 0; nf < 4; ++nf) {
    const int col = ccol0 + nf * 16;
    const float bvv = bias[col];
#pragma unroll
    for (int mf = 0; mf < 4; ++mf) {
#pragma unroll
      for (int j = 0; j < 4; ++j) {
        const int row = crow0 + mf * 16 + j;
        float v = fmaxf(acc[mf][nf][j] + bvv, 0.f);
        C[(size_t)row * N + col] = (_Float16)v;
      }
    }
  }
}

// ---------------- GEMM2 + fused spline epilogue -----------------------------
// K-loop: round-8 verified stage/vmcnt ledger, phases merged pairwise into
// 4 regions/iter (8 barriers vs 16). Region: {read qa (+B hdr); stages; wait;
// barrier; MFQ(qa); read qb (drains under qa's MFMAs); MFQ(qb); barrier}.
__global__ __launch_bounds__(512, 2) void k_gemm2s(
    const _Float16* __restrict__ A, const _Float16* __restrict__ Bt,
    const float* __restrict__ bias, const float* __restrict__ y,
    float* __restrict__ outp, float* __restrict__ gpart, int M) {
  constexpr int K = HDIM;       // 2048
  constexpr int K2 = K * 2;     // row bytes
  constexpr int NT = K / 64;    // 32 K-tiles
  constexpr int ITERS = NT / 2; // 16

  __shared__ char smem[131072];
  __shared__ float red[512];

  const int t = threadIdx.x;
  const int l = t & 63;
  const int w = t >> 6;
  const int wm = w >> 2;
  const int wn = w & 3;
  const int rlo = l & 15;
  const int khi = l >> 4;
  const int wOff = w * 1024;

  // XCD mapping: each XCD owns 8 contiguous by rows, iterates bx-major
  int bx = blockIdx.x, by = blockIdx.y;   // 26 x 64
  {
    const int lin = by * 26 + bx;
    const int xcd = lin & 7;
    const int slot = lin >> 3;
    bx = slot >> 3;
    by = xcd * 8 + (slot & 7);
  }
  const int tileM = by * 256;
  const int tileN = bx * 256;

  // staging source decode: LDS phys -> logical (involution: bit9 -> bit5)
  int rowj[2], kbj[2];
#pragma unroll
  for (int j = 0; j < 2; ++j) {
    const int phys = j * 8192 + t * 16;
    const int b = phys ^ (((phys >> 9) & 1) << 5);
    rowj[j] = ((b >> 11) << 4) + ((b >> 6) & 15);
    kbj[j] = (((b >> 10) & 1) << 6) + (b & 63);
  }
  const char* pA[2][2];
  const char* pB[2][2];
#pragma unroll
  for (int half = 0; half < 2; ++half)
#pragma unroll
    for (int j = 0; j < 2; ++j) {
      pA[half][j] = (const char*)A + (size_t)(tileM + half * 128 + rowj[j]) * K2 + kbj[j];
      pB[half][j] = (const char*)Bt + (size_t)(tileN + half * 128 + rowj[j]) * K2 + kbj[j];
    }

  auto lds3 = (__attribute__((address_space(3))) char*)smem;

#define LDSA(d, half) ((d) * 32768 + (half) * 16384)
#define LDSB(d, half) (65536 + (d) * 32768 + (half) * 16384)
#define GLDS(srcp, ldsoff)                                                                   \
  __builtin_amdgcn_global_load_lds(                                                           \
      (const __attribute__((address_space(1))) uint32_t*)(srcp),                              \
      (__attribute__((address_space(3))) uint32_t*)(lds3 + (ldsoff) + wOff), 16, 0, 0)
#define STG(op, d, half, kt)                                                                  \
  do {                                                                                        \
    GLDS(p##op[half][0] + (size_t)(kt) * 128, LDS##op(d, half));                              \
    GLDS(p##op[half][1] + (size_t)(kt) * 128, LDS##op(d, half) + 8192);                       \
  } while (0)
#define VM(n) asm volatile("s_waitcnt vmcnt(" #n ")" ::: "memory")
#define NOSTG ((void)0)
#define NOW ((void)0)
#define CFENCE asm volatile("" ::: "memory")

  const int swz = (rlo & 8) ? 32 : 0;
  const int lane16 = rlo * 64 + ((khi * 16) ^ swz);
  const int aW = wm * 8192 + lane16;
  const int bW = 65536 + wn * 4096 + lane16;

  half8v b000, b001, b010, b011, b100, b101, b110, b111;
  f32x4 acc[8][4];
#pragma unroll
  for (int i = 0; i < 8; ++i)
#pragma unroll
    for (int j = 0; j < 4; ++j) acc[i][j] = (f32x4){0.f, 0.f, 0.f, 0.f};

#define MF(fi, gj, av, bv) \
  acc[fi][gj] = __builtin_amdgcn_mfma_f32_16x16x32_f16(av, bv, acc[fi][gj], 0, 0, 0)

#define RD4(v0, v1, v2, v3, d, q)                                                             \
  do {                                                                                        \
    const int aB = (d) * 32768 + ((q) >> 1) * 16384 + ((q) & 1) * 4096 + aW;                  \
    v0 = *(const half8v*)(smem + aB);                                                         \
    v1 = *(const half8v*)(smem + aB + 1024);                                                  \
    v2 = *(const half8v*)(smem + aB + 2048);                                                  \
    v3 = *(const half8v*)(smem + aB + 3072);                                                  \
  } while (0)

#define HDRB(d)                                                                               \
  do {                                                                                        \
    const int bB = (d) * 32768 + bW;                                                          \
    b000 = *(const half8v*)(smem + bB);                                                       \
    b001 = *(const half8v*)(smem + bB + 1024);                                                \
    b010 = *(const half8v*)(smem + bB + 2048);                                                \
    b011 = *(const half8v*)(smem + bB + 3072);                                                \
    b100 = *(const half8v*)(smem + bB + 16384);                                               \
    b101 = *(const half8v*)(smem + bB + 17408);                                               \
    b110 = *(const half8v*)(smem + bB + 18432);                                               \
    b111 = *(const half8v*)(smem + bB + 19456);                                               \
  } while (0)

// 16 MFMAs of quadrant q (8 independent, then dependent partners)
#define MFQ4(q, v0, v1, v2, v3)                                                               \
  {                                                                                           \
    constexpr int f0 = ((q) >> 1) * 4 + ((q) & 1) * 2;                                        \
    MF(f0 + 0, 0, v0, b000); MF(f0 + 0, 1, v0, b010);                                         \
    MF(f0 + 0, 2, v0, b100); MF(f0 + 0, 3, v0, b110);                                         \
    MF(f0 + 1, 0, v2, b000); MF(f0 + 1, 1, v2, b010);                                         \
    MF(f0 + 1, 2, v2, b100); MF(f0 + 1, 3, v2, b110);                                         \
    MF(f0 + 0, 0, v1, b001); MF(f0 + 0, 1, v1, b011);                                         \
    MF(f0 + 0, 2, v1, b101); MF(f0 + 0, 3, v1, b111);                                         \
    MF(f0 + 1, 0, v3, b001); MF(f0 + 1, 1, v3, b011);                                         \
    MF(f0 + 1, 2, v3, b101); MF(f0 + 1, 3, v3, b111);                                         \
  }

// merged region: quadrants qa,qb of buffer d; HDR=1 reloads B (q0 regions)
#define REGION(d, HDR, qa, qb, STAGES, WAITS)                                                 \
  do {                                                                                        \
    half8v x0, x1, x2, x3, z0, z1, z2, z3;                                                    \
    RD4(x0, x1, x2, x3, d, qa);                                                               \
    if (HDR) HDRB(d);                                                                         \
    STAGES;                                                                                   \
    WAITS;                                                                                    \
    CFENCE;                                                                                   \
    __builtin_amdgcn_s_barrier();                                                             \
    CFENCE;                                                                                   \
    __builtin_amdgcn_s_setprio(1);                                                            \
    MFQ4(qa, x0, x1, x2, x3);                                                                 \
    __builtin_amdgcn_s_setprio(0);                                                            \
    RD4(z0, z1, z2, z3, d, qb);                                                               \
    __builtin_amdgcn_s_setprio(1);                                                            \
    MFQ4(qb, z0, z1, z2, z3);                                                                 \
    __builtin_amdgcn_s_setprio(0);                                                            \
    CFENCE;                                                                                   \
    __builtin_amdgcn_s_barrier();                                                             \
  } while (0)

  // prologue: tile0 full (8 loads) -> buf0; tile1 B+A-h0 (6 loads) -> buf1
  STG(B, 0, 0, 0);
  STG(B, 0, 1, 0);
  STG(A, 0, 0, 0);
  STG(A, 0, 1, 0);
  STG(B, 1, 0, 1);
  STG(B, 1, 1, 1);
  STG(A, 1, 0, 1);
  VM(6);
  CFENCE;
  __builtin_amdgcn_s_barrier();

  // steady state (ledger simulated from prologue; outstanding at each VM:
  // R2's VM(8) drains tile kt+1 B+A-h0; R3's VM(10) drains A(1,1,kt+1);
  // R4's VM(6) drains tile kt+2 B+A -> entry condition 6 restored).
  for (int it = 0; it < ITERS - 1; ++it) {
    const int kt = 2 * it;
    REGION(0, 1, 0, 1, STG(A, 1, 1, kt + 1); STG(B, 0, 0, kt + 2), NOW);
    REGION(0, 0, 2, 3, STG(B, 0, 1, kt + 2); STG(A, 0, 0, kt + 2), VM(8));
    REGION(1, 1, 0, 1, STG(A, 0, 1, kt + 2); STG(B, 1, 0, kt + 3), VM(10));
    REGION(1, 0, 2, 3, STG(B, 1, 1, kt + 3); STG(A, 1, 0, kt + 3), VM(6));
  }
  // tail: tiles NT-2 (buf0), NT-1 (buf1)
  REGION(0, 1, 0, 1, STG(A, 1, 1, NT - 1), NOW);
  REGION(0, 0, 2, 3, NOSTG, VM(2));
  REGION(1, 1, 0, 1, NOSTG, VM(0));
  REGION(1, 0, 2, 3, NOSTG, NOW);

#undef REGION
#undef MFQ4
#undef HDRB
#undef RD4
#undef MF
#undef STG
#undef GLDS
#undef LDSA
#undef LDSB

  // ---- fused epilogue (round-8 verified) -----------------------------------
  const int RCt = (bx < 25) ? 245 : 147;
  const int nd  = (bx < 25) ? 5 : 3;

  // C-tile -> LDS col-major: addr(c,r) = c*512 + ((2r) ^ ((c&31)<<4))
#pragma unroll
  for (int fi = 0; fi < 8; ++fi) {
    const int r0l = (((fi >> 2) * 2 + wm) << 6) + ((fi & 3) << 4) + khi * 4;
#pragma unroll
    for (int gj = 0; gj < 4; ++gj) {
      const int c = (((gj >> 1) * 4 + wn) << 5) + ((gj & 1) << 4) + rlo;
      if (c < RCt) {
        const float bvv = bias[245 * bx + c];
        const int cb = c * 512;
        const int cs = (c & 31) << 4;
#pragma unroll
        for (int jp = 0; jp < 2; ++jp) {
          const int r = r0l + jp * 2;
          const unsigned short lo =
              __builtin_bit_cast(unsigned short, (_Float16)(acc[fi][gj][jp * 2] + bvv));
          const unsigned short hi =
              __builtin_bit_cast(unsigned short, (_Float16)(acc[fi][gj][jp * 2 + 1] + bvv));
          *(uint32_t*)(smem + cb + ((2 * r) ^ cs)) = (uint32_t)lo | ((uint32_t)hi << 16);
        }
      }
    }
  }
  __syncthreads();

  // spline: row r = t&255; dim d = pass*2 + (t>>8)
  const int r = t & 255;
  const int rg = tileM + r;
  float yv_[3];
#pragma unroll
  for (int pass = 0; pass < 3; ++pass) {
    const int d = pass * 2 + (t >> 8);
    yv_[pass] = (d < nd) ? y[(size_t)rg * DYDIM + 5 * bx + d] : 0.f;
  }

#define LDC(p) ((float)*(const _Float16*)(smem + (size_t)(dD * 49 + (p)) * 512 + \
                                          ((2 * r) ^ (((dD * 49 + (p)) & 31) << 4))))
  float lsum = 0.f;
#pragma unroll
  for (int pass = 0; pass < 3; ++pass) {
    const int dD = pass * 2 + (t >> 8);
    if (dD < nd) {
      float qw[16], qh[16], qd[17];
#pragma unroll
      for (int p = 0; p < 16; ++p) { qw[p] = LDC(p); qh[p] = LDC(16 + p); }
#pragma unroll
      for (int p = 0; p < 17; ++p) qd[p] = LDC(32 + p);

      float mw = qw[0], mh = qh[0];
#pragma unroll
      for (int p = 1; p < 16; ++p) { mw = fmaxf(mw, qw[p]); mh = fmaxf(mh, qh[p]); }
      float ew[16], eh[16];
      float sw2 = 0.f, sh = 0.f;
#pragma unroll
      for (int p = 0; p < 16; ++p) {
        ew[p] = __expf(qw[p] - mw);
        eh[p] = __expf(qh[p] - mh);
        sw2 += ew[p];
        sh += eh[p];
      }
      const float rw = 0.984f / sw2, rh = 0.984f / sh;
      const float yv = yv_[pass];

      float cws = 0.f, chs = 0.f, xk = 0.f, yk = 0.f, wk = 1.f, hk = 1.f;
      float du0 = qd[0], du1 = qd[1];
#pragma unroll
      for (int j = 0; j < 16; ++j) {
        float wj = 0.001f + rw * ew[j];
        float hj = 0.001f + rh * eh[j];
        if (yv >= cws) { xk = cws; yk = chs; wk = wj; hk = hj; du0 = qd[j]; du1 = qd[j + 1]; }
        cws += wj;
        chs += hj;
      }
      const float dk  = 0.001f + fmaxf(du0, 0.f) + log1pf(__expf(-fabsf(du0)));
      const float dk1 = 0.001f + fmaxf(du1, 0.f) + log1pf(__expf(-fabsf(du1)));

      const float s = hk / wk;
      const float tt = (yv - xk) / wk;
      const float omt = 1.f - tt;
      const float dnm = s + (dk1 + dk - 2.f * s) * tt * omt;
      const float o = yk + hk * (s * tt * tt + dk * tt * omt) / dnm;
      const float dr = s * s * (dk1 * tt * tt + 2.f * s * tt * omt + dk * omt * omt) / (dnm * dnm);

      outp[(size_t)rg * DYDIM + 5 * bx + dD] = o;
      lsum += __logf(dr);
    }
  }
#undef LDC
  red[t] = lsum;
  __syncthreads();
  if (t < 256)
    gpart[(size_t)bx * B_ROWS + (tileM + t)] = red[t] + red[t + 256];
}

// ---------------- dlogp reduce ----------------
__global__ void k_dlogp_reduce(const float* __restrict__ gpart, float* __restrict__ dlogp) {
  int b = blockIdx.x * 256 + threadIdx.x;
  float s = 0.f;
  for (int tt = 0; tt < NTILES; ++tt) s += gpart[(size_t)tt * B_ROWS + b];
  dlogp[b] = s;
}

// ---------------- launch ----------------
extern "C" void kernel_launch(void* const* d_in, const int* in_sizes, int n_in,
                              void* d_out, int out_size, void* d_ws, size_t ws_size,
                              hipStream_t stream) {
  const float* x  = (const float*)d_in[0];
  const float* y  = (const float*)d_in[1];
  const float* W1 = (const float*)d_in[2];
  const float* b1 = (const float*)d_in[3];
  const float* W2 = (const float*)d_in[4];
  const float* b2 = (const float*)d_in[5];
  float* out = (float*)d_out;
  float* dlogp = out + (size_t)B_ROWS * DYDIM;

  char* ws = (char*)d_ws;
  _Float16* w2p = (_Float16*)ws;
  _Float16* h   = w2p + (size_t)W2PROWS * HDIM;
  _Float16* xb  = h + (size_t)B_ROWS * HDIM;
  _Float16* w1t = xb + (size_t)B_ROWS * DX;
  float* gpart  = (float*)(w1t + (size_t)HDIM * DX);

  k_f32_to_f16<<<(B_ROWS * DX + 255) / 256, 256, 0, stream>>>(x, xb, B_ROWS * DX);
  k_transpose_f16<<<dim3(HDIM / 32, DX / 32), dim3(32, 8), 0, stream>>>(W1, w1t, DX, HDIM);
  k_transpose_perm<<<dim3(NCOL / 32, HDIM / 32), dim3(32, 8), 0, stream>>>(W2, w2p);

  k_gemm1<<<dim3(HDIM / 128, B_ROWS / 128), 256, 0, stream>>>(
      xb, w1t, b1, h, B_ROWS, HDIM, DX);

  k_gemm2s<<<dim3(NTILES, B_ROWS / 256), 512, 0, stream>>>(
      h, w2p, b2, y, out, gpart, B_ROWS);

  k_dlogp_reduce<<<B_ROWS / 256, 256, 0, stream>>>(gpart, dlogp);
}